// Round 4
// baseline (313.858 us; speedup 1.0000x reference)
//
#include <hip/hip_runtime.h>
#include <hip/hip_bf16.h>
#include <math.h>

#define NEGV (-1000000000.0f)
constexpr int Bb = 8, Ll = 4096, Hh = 512, Cc = 64, Aa = 512;

typedef float f32x4 __attribute__((ext_vector_type(4)));
typedef short s16x8 __attribute__((ext_vector_type(8)));

__device__ inline ushort f2bf(float f) {
  union { float f; uint u; } v; v.f = f;
  uint u = v.u;
  return (ushort)((u + 0x7FFFu + ((u >> 16) & 1u)) >> 16);
}

__device__ inline uint bfpack2(float x, float y) {
  __hip_bfloat162 h = __float22bfloat162_rn(make_float2(x, y));
  union { __hip_bfloat162 h; uint u; } v; v.h = h;
  return v.u;
}

__device__ inline s16x8 pack8(const float4 a, const float4 b) {
  union { uint4 u4; s16x8 s; } cv;
  cv.u4 = (uint4){bfpack2(a.x, a.y), bfpack2(a.z, a.w),
                  bfpack2(b.x, b.y), bfpack2(b.z, b.w)};
  return cv.s;
}

// ---------------------------------------------------------------------------
// k_init: logits[b][l] = sb + log1p(max(cnt,0));  cmax[b] = max count.
// ---------------------------------------------------------------------------
__global__ void k_init(const int* __restrict__ cnt, const float* __restrict__ sb,
                       float* __restrict__ logits, int* __restrict__ cmax) {
  int i = blockIdx.x * 256 + threadIdx.x;  // 0..32767
  int c = cnt[i];
  logits[i] = sb[0] + log1pf(fmaxf((float)c, 0.f));
  int m = c;
#pragma unroll
  for (int s = 32; s; s >>= 1) m = max(m, __shfl_xor(m, s));
  if ((threadIdx.x & 63) == 0) atomicMax(&cmax[i >> 12], m);
}

// ---------------------------------------------------------------------------
// kT_pw: pwT[a][k] = bf16(pw[k][a]).  Grid 64 blocks (8 ktiles x 8 atiles).
// ---------------------------------------------------------------------------
__global__ void kT_pw(const float* __restrict__ pw, ushort* __restrict__ pwT) {
  __shared__ ushort s[64][65];
  const int k0 = (blockIdx.x >> 3) * 64, a0 = (blockIdx.x & 7) * 64;
  const int t = threadIdx.x;
#pragma unroll
  for (int i = 0; i < 16; ++i) {
    int e = t + i * 256;
    int kk = e >> 6, aa = e & 63;
    s[aa][kk] = f2bf(pw[(size_t)(k0 + kk) * Aa + a0 + aa]);
  }
  __syncthreads();
#pragma unroll
  for (int i = 0; i < 16; ++i) {
    int e = t + i * 256;
    int aa = e >> 6, kk = e & 63;
    pwT[(size_t)(a0 + aa) * Hh + k0 + kk] = s[aa][kk];
  }
}

// ---------------------------------------------------------------------------
// k0_gemm (no-LDS): logits += sum_a tanh((hid @ pw)[m][a] + pb[a]) * sw[a]
// Each wave: 64x64 tile (4x4 frags of 16x16x32), K=512 in 16 steps.
// A-frags: 2x float4 global + in-reg bf16 pack (hid natural [m][k] layout).
// B-frags: direct 16B bf16 loads from pwT [n][k]. No LDS, no barriers.
// Grid (512 mtiles, 2), 4 waves/block spanning n. 16 waves/CU.
// ---------------------------------------------------------------------------
__global__ __launch_bounds__(256, 4) void k0_gemm(
    const float* __restrict__ hid, const ushort* __restrict__ pwT,
    const float* __restrict__ pb, const float* __restrict__ sw,
    float* __restrict__ logits) {
  const int tid = threadIdx.x;
  const int w = tid >> 6, lane = tid & 63;
  const int lc = lane & 15, lq = lane >> 4;
  const int m0 = blockIdx.x * 64;
  const int n0 = (blockIdx.y * 4 + w) * 64;

  f32x4 acc[4][4];
#pragma unroll
  for (int mi = 0; mi < 4; ++mi)
#pragma unroll
    for (int ni = 0; ni < 4; ++ni) acc[mi][ni] = (f32x4){0.f, 0.f, 0.f, 0.f};

  const float* Abase = hid + ((size_t)(m0 + lc)) * Hh + lq * 8;
  const ushort* Bbase = pwT + ((size_t)(n0 + lc)) * Hh + lq * 8;

  for (int kb = 0; kb < 16; ++kb) {
    s16x8 af[4], bf[4];
#pragma unroll
    for (int mi = 0; mi < 4; ++mi) {
      const float* ap = Abase + (size_t)mi * 16 * Hh + kb * 32;
      float4 a0 = *(const float4*)(ap);
      float4 a1 = *(const float4*)(ap + 4);
      af[mi] = pack8(a0, a1);
    }
#pragma unroll
    for (int ni = 0; ni < 4; ++ni)
      bf[ni] = *(const s16x8*)(Bbase + (size_t)ni * 16 * Hh + kb * 32);
#pragma unroll
    for (int mi = 0; mi < 4; ++mi)
#pragma unroll
      for (int ni = 0; ni < 4; ++ni)
        acc[mi][ni] = __builtin_amdgcn_mfma_f32_16x16x32_bf16(
            af[mi], bf[ni], acc[mi][ni], 0, 0, 0);
  }

  // epilogue: tanh(x + pb[n]) * sw[n], reduce over n, atomicAdd into logits
  float pbv[4], swv[4];
#pragma unroll
  for (int ni = 0; ni < 4; ++ni) {
    int n = n0 + ni * 16 + lc;
    pbv[ni] = pb[n];
    swv[ni] = sw[n];
  }
#pragma unroll
  for (int mi = 0; mi < 4; ++mi) {
#pragma unroll
    for (int r = 0; r < 4; ++r) {
      float s = 0.f;
#pragma unroll
      for (int ni = 0; ni < 4; ++ni) {
        float x = acc[mi][ni][r] + pbv[ni];
        float e = __expf(2.f * x);
        float th = 1.f - 2.f / (e + 1.f);
        s = fmaf(th, swv[ni], s);
      }
      s += __shfl_xor(s, 1);
      s += __shfl_xor(s, 2);
      s += __shfl_xor(s, 4);
      s += __shfl_xor(s, 8);
      if (lc == 0) {
        int m = m0 + mi * 16 + lq * 4 + r;
        atomicAdd(&logits[m], s);
      }
    }
  }
}

// ---------------------------------------------------------------------------
// K2: actT[b][c][l] = relu(act[b][l][c]);  dinv[b][l] = 1/max(sum_c relu, 1)
// ---------------------------------------------------------------------------
__global__ void k2_transpose(const float* __restrict__ act,
                             float* __restrict__ actT,
                             float* __restrict__ dinv) {
  __shared__ float t64[64][65];
  const int b = blockIdx.x >> 6;
  const int l0 = (blockIdx.x & 63) * 64;
  const int tid = threadIdx.x;
#pragma unroll
  for (int i = 0; i < 16; ++i) {
    int e = tid + i * 256;
    int l = e >> 6, c = e & 63;
    float v = act[((size_t)(b * Ll + l0 + l)) * Cc + c];
    t64[l][c] = fmaxf(v, 0.f);
  }
  __syncthreads();
  if (tid < 64) {
    float s = 0.f;
#pragma unroll 8
    for (int c = 0; c < 64; ++c) s += t64[tid][c];
    dinv[b * Ll + l0 + tid] = 1.0f / fmaxf(s, 1.0f);
  }
#pragma unroll
  for (int i = 0; i < 16; ++i) {
    int e = tid + i * 256;
    int c = e >> 6, lq = e & 63;
    actT[((size_t)(b * Cc + c)) * Ll + l0 + lq] = t64[lq][c];
  }
}

// ---------------------------------------------------------------------------
// K3: per (b,c) row softmax over L -> weights output (fp32) + bf16 copy.
// ---------------------------------------------------------------------------
__global__ void k3_softmax(const float* __restrict__ actT,
                           const float* __restrict__ logits,
                           float* __restrict__ wout,
                           ushort* __restrict__ wb16,
                           int* __restrict__ hasany) {
  __shared__ float rmax[4], rcnt[4], rsum[4];
  const int bid = blockIdx.x;  // b*64+c
  const int b = bid >> 6;
  const int tid = threadIdx.x;
  const float* arow = actT + (size_t)bid * Ll;

  float xs[16];
  float lmax = NEGV, fcnt = 0.f;
#pragma unroll
  for (int i = 0; i < 16; ++i) {
    int l = tid + i * 256;
    float a = arow[l];
    float x;
    if (a > 0.f) {
      x = logits[b * Ll + l] + log1pf(a);
      fcnt += 1.f;
    } else {
      x = NEGV;
    }
    xs[i] = x;
    lmax = fmaxf(lmax, x);
  }
#pragma unroll
  for (int m = 32; m >= 1; m >>= 1) {
    lmax = fmaxf(lmax, __shfl_xor(lmax, m));
    fcnt += __shfl_xor(fcnt, m);
  }
  if ((tid & 63) == 0) { rmax[tid >> 6] = lmax; rcnt[tid >> 6] = fcnt; }
  __syncthreads();
  float m4 = fmaxf(fmaxf(rmax[0], rmax[1]), fmaxf(rmax[2], rmax[3]));
  float call = rcnt[0] + rcnt[1] + rcnt[2] + rcnt[3];

  float lsum = 0.f;
#pragma unroll
  for (int i = 0; i < 16; ++i) {
    float e = expf(xs[i] - m4);
    xs[i] = e;
    lsum += e;
  }
#pragma unroll
  for (int m = 32; m >= 1; m >>= 1) lsum += __shfl_xor(lsum, m);
  if ((tid & 63) == 0) rsum[tid >> 6] = lsum;
  __syncthreads();
  float s = rsum[0] + rsum[1] + rsum[2] + rsum[3];
  int any = call > 0.5f;
  float inv = any ? 1.0f / s : 0.f;
#pragma unroll
  for (int i = 0; i < 16; ++i) {
    float wv = xs[i] * inv;
    wout[(size_t)bid * Ll + tid + i * 256] = wv;
    wb16[(size_t)bid * Ll + tid + i * 256] = f2bf(wv);
  }
  if (tid == 0) hasany[bid] = any;
}

// ---------------------------------------------------------------------------
// K5: bf16 MFMA partial GEMM: pbuf[kz][b][c][h] = sum_{l in slice} w*hid.
// ---------------------------------------------------------------------------
__global__ __launch_bounds__(256) void k5_mfma(
    const ushort* __restrict__ wb16, const float* __restrict__ hid,
    float* __restrict__ pbuf) {
  const int b = blockIdx.x, nt = blockIdx.y, kz = blockIdx.z;
  const int tid = threadIdx.x;
  const int w = tid >> 6, lane = tid & 63;
  const int lc = lane & 15, lq = lane >> 4;
  const int h0 = nt * 128 + w * 32;

  f32x4 acc[4][2];
#pragma unroll
  for (int mi = 0; mi < 4; ++mi)
#pragma unroll
    for (int ni = 0; ni < 2; ++ni) acc[mi][ni] = (f32x4){0.f, 0.f, 0.f, 0.f};

  const ushort* Abase =
      wb16 + (size_t)b * Cc * Ll + (size_t)lc * Ll + kz * 256 + lq * 8;
  const float* Bbase =
      hid + ((size_t)(b * Ll + kz * 256 + lq * 8)) * Hh + h0 + lc;

  for (int kb = 0; kb < 8; ++kb) {
    s16x8 af[4];
#pragma unroll
    for (int mi = 0; mi < 4; ++mi)
      af[mi] = *(const s16x8*)(Abase + (size_t)mi * 16 * Ll + kb * 32);
    s16x8 bf[2];
#pragma unroll
    for (int ni = 0; ni < 2; ++ni) {
      const float* bp = Bbase + (size_t)kb * 32 * Hh + ni * 16;
      uint u0 = bfpack2(bp[0 * Hh], bp[1 * Hh]);
      uint u1 = bfpack2(bp[2 * Hh], bp[3 * Hh]);
      uint u2 = bfpack2(bp[4 * Hh], bp[5 * Hh]);
      uint u3 = bfpack2(bp[6 * Hh], bp[7 * Hh]);
      union { uint4 u4; s16x8 s; } cv;
      cv.u4 = (uint4){u0, u1, u2, u3};
      bf[ni] = cv.s;
    }
#pragma unroll
    for (int mi = 0; mi < 4; ++mi)
#pragma unroll
      for (int ni = 0; ni < 2; ++ni)
        acc[mi][ni] = __builtin_amdgcn_mfma_f32_16x16x32_bf16(
            af[mi], bf[ni], acc[mi][ni], 0, 0, 0);
  }

  const size_t obase = ((size_t)(kz * Bb + b)) * Cc * Hh;
#pragma unroll
  for (int mi = 0; mi < 4; ++mi)
#pragma unroll
    for (int ni = 0; ni < 2; ++ni)
#pragma unroll
      for (int r = 0; r < 4; ++r)
        pbuf[obase + (size_t)(mi * 16 + lq * 4 + r) * Hh + h0 + ni * 16 + lc] =
            acc[mi][ni][r];
}

// ---------------------------------------------------------------------------
// K6: reduce 16 partials + fallback substitution.
// ---------------------------------------------------------------------------
__global__ void k6_reduce(const float* __restrict__ pbuf,
                          const int* __restrict__ hasany,
                          const float* __restrict__ hid,
                          float* __restrict__ cctx) {
  int idx = blockIdx.x * 256 + threadIdx.x;  // 0..262143
  float s = 0.f;
#pragma unroll
  for (int z = 0; z < 16; ++z) s += pbuf[(size_t)z * 262144 + idx];
  int bc = idx >> 9, b = idx >> 15, h = idx & 511;
  cctx[idx] = hasany[bc] ? s : hid[((size_t)(b * Ll + Ll - 1)) * Hh + h];
}

// ---------------------------------------------------------------------------
// K7: attended = mask ? (mix @ cctx) * gate : hidden
// ---------------------------------------------------------------------------
__global__ __launch_bounds__(256, 2) void k7_out(
    const float* __restrict__ hid, const float* __restrict__ act,
    const float* __restrict__ dinv, const float* __restrict__ cctx,
    const int* __restrict__ mask, const int* __restrict__ cnt,
    const int* __restrict__ cmax, float* __restrict__ out) {
  __shared__ float mix[32 * 68];
  __shared__ float gateb[32];
  __shared__ int maskb[32];
  const int b = blockIdx.x;
  const int l0 = blockIdx.y * 32;
  const int tid = threadIdx.x;
  const float maxcf = fmaxf((float)cmax[b], 1.0f);

#pragma unroll
  for (int i = 0; i < 2; ++i) {
    int q = tid + i * 256;
    int t = q >> 4, cq = q & 15;
    float4 a4 = *(const float4*)(act + ((size_t)(b * Ll + l0 + t)) * Cc + cq * 4);
    float dv = dinv[b * Ll + l0 + t];
    a4.x = fmaxf(a4.x, 0.f) * dv;
    a4.y = fmaxf(a4.y, 0.f) * dv;
    a4.z = fmaxf(a4.z, 0.f) * dv;
    a4.w = fmaxf(a4.w, 0.f) * dv;
    *(float4*)(mix + t * 68 + cq * 4) = a4;
  }
  if (tid < 32) {
    int l = l0 + tid;
    maskb[tid] = mask[b * Ll + l];
    gateb[tid] = 1.0f + (float)cnt[b * Ll + l] / maxcf;
  }
  __syncthreads();

  const int tt = tid >> 6;
  const int h = (tid & 63) * 8;
  float acc[8][8];
#pragma unroll
  for (int t = 0; t < 8; ++t)
#pragma unroll
    for (int u = 0; u < 8; ++u) acc[t][u] = 0.f;

#pragma unroll 4
  for (int c = 0; c < 64; ++c) {
    float4 cA = *(const float4*)(cctx + ((size_t)(b * Cc + c)) * Hh + h);
    float4 cB = *(const float4*)(cctx + ((size_t)(b * Cc + c)) * Hh + h + 4);
    float cv[8] = {cA.x, cA.y, cA.z, cA.w, cB.x, cB.y, cB.z, cB.w};
#pragma unroll
    for (int t = 0; t < 8; ++t) {
      float mv = mix[(tt * 8 + t) * 68 + c];
#pragma unroll
      for (int u = 0; u < 8; ++u) acc[t][u] = fmaf(mv, cv[u], acc[t][u]);
    }
  }
#pragma unroll
  for (int t = 0; t < 8; ++t) {
    int tok = tt * 8 + t;
    size_t off = ((size_t)(b * Ll + l0 + tok)) * Hh + h;
    float4 o1, o2;
    if (maskb[tok]) {
      float g = gateb[tok];
      o1 = make_float4(acc[t][0] * g, acc[t][1] * g, acc[t][2] * g, acc[t][3] * g);
      o2 = make_float4(acc[t][4] * g, acc[t][5] * g, acc[t][6] * g, acc[t][7] * g);
    } else {
      o1 = *(const float4*)(hid + off);
      o2 = *(const float4*)(hid + off + 4);
    }
    *(float4*)(out + off) = o1;
    *(float4*)(out + off + 4) = o2;
  }
}

// ---------------------------------------------------------------------------
extern "C" void kernel_launch(void* const* d_in, const int* in_sizes, int n_in,
                              void* d_out, int out_size, void* d_ws,
                              size_t ws_size, hipStream_t stream) {
  const float* hid = (const float*)d_in[0];
  const int* mask = (const int*)d_in[1];
  const int* cnt = (const int*)d_in[2];
  const float* act = (const float*)d_in[3];
  const float* pw = (const float*)d_in[4];
  const float* pb = (const float*)d_in[5];
  const float* sw = (const float*)d_in[6];
  const float* sb = (const float*)d_in[7];

  float* out_att = (float*)d_out;                 // (B,L,H)
  float* out_w = out_att + (size_t)Bb * Ll * Hh;  // (B,C,L)

  float* ws = (float*)d_ws;
  float* cctx = ws;                               // 262144 f
  int* cmaxi = (int*)(ws + 262144);               // 8 i
  float* logits = ws + 262152;                    // 32768 f
  float* actT = ws + 294920;                      // 2097152 f
  float* dinv = ws + 2392072;                     // 32768 f
  int* hasany = (int*)(ws + 2424840);             // 512 i
  ushort* pwT = (ushort*)(ws + 2425352);          // 262144 bf16
  ushort* wb16 = (ushort*)(ws + 2556424);         // 2097152 bf16
  float* pbuf = ws + 3605000;                     // 4194304 f (16 MB)

  hipMemsetAsync(cmaxi, 0, 8 * sizeof(int), stream);

  k_init<<<128, 256, 0, stream>>>(cnt, sb, logits, cmaxi);
  kT_pw<<<64, 256, 0, stream>>>(pw, pwT);
  k0_gemm<<<dim3(512, 2), 256, 0, stream>>>(hid, pwT, pb, sw, logits);
  k2_transpose<<<512, 256, 0, stream>>>(act, actT, dinv);
  k3_softmax<<<512, 256, 0, stream>>>(actT, logits, out_w, wb16, hasany);
  k5_mfma<<<dim3(8, 4, 16), 256, 0, stream>>>(wb16, hid, pbuf);
  k6_reduce<<<1024, 256, 0, stream>>>(pbuf, hasany, hid, cctx);
  k7_out<<<dim3(8, 128), 256, 0, stream>>>(hid, act, dinv, cctx, mask, cnt,
                                           cmaxi, out_att);
}

// Round 5
// 281.994 us; speedup vs baseline: 1.1130x; 1.1130x over previous
//
#include <hip/hip_runtime.h>
#include <hip/hip_bf16.h>
#include <math.h>

#define NEGV (-1000000000.0f)
constexpr int Bb = 8, Ll = 4096, Hh = 512, Cc = 64, Aa = 512;

typedef float f32x4 __attribute__((ext_vector_type(4)));
typedef short s16x8 __attribute__((ext_vector_type(8)));

__device__ inline ushort f2bf(float f) {
  union { float f; uint u; } v; v.f = f;
  uint u = v.u;
  return (ushort)((u + 0x7FFFu + ((u >> 16) & 1u)) >> 16);
}

__device__ inline uint bfpack2(float x, float y) {
  __hip_bfloat162 h = __float22bfloat162_rn(make_float2(x, y));
  union { __hip_bfloat162 h; uint u; } v; v.h = h;
  return v.u;
}

#define GLOAD_LDS16(gptr, lptr)                                              \
  __builtin_amdgcn_global_load_lds(                                          \
      (const __attribute__((address_space(1))) uint*)(gptr),                 \
      (__attribute__((address_space(3))) uint*)(lptr), 16, 0, 0)

// ---------------------------------------------------------------------------
// k_conv: hidb = bf16(hid).  8 elements/thread, 8192 blocks.
// ---------------------------------------------------------------------------
__global__ void k_conv(const float* __restrict__ hid,
                       ushort* __restrict__ hidb) {
  size_t i = ((size_t)blockIdx.x * 256 + threadIdx.x) * 8;
  float4 a = *(const float4*)(hid + i);
  float4 b = *(const float4*)(hid + i + 4);
  uint4 p = {bfpack2(a.x, a.y), bfpack2(a.z, a.w), bfpack2(b.x, b.y),
             bfpack2(b.z, b.w)};
  *(uint4*)(hidb + i) = p;
}

// ---------------------------------------------------------------------------
// k_init: logits[b][l] = sb + log1p(max(cnt,0));  cmax[b] = max count.
// ---------------------------------------------------------------------------
__global__ void k_init(const int* __restrict__ cnt, const float* __restrict__ sb,
                       float* __restrict__ logits, int* __restrict__ cmax) {
  int i = blockIdx.x * 256 + threadIdx.x;  // 0..32767
  int c = cnt[i];
  logits[i] = sb[0] + log1pf(fmaxf((float)c, 0.f));
  int m = c;
#pragma unroll
  for (int s = 32; s; s >>= 1) m = max(m, __shfl_xor(m, s));
  if ((threadIdx.x & 63) == 0) atomicMax(&cmax[i >> 12], m);
}

// ---------------------------------------------------------------------------
// kT_pw: pwT[a][k] = bf16(pw[k][a]).  Grid 64 blocks (8 ktiles x 8 atiles).
// ---------------------------------------------------------------------------
__global__ void kT_pw(const float* __restrict__ pw, ushort* __restrict__ pwT) {
  __shared__ ushort s[64][65];
  const int k0 = (blockIdx.x >> 3) * 64, a0 = (blockIdx.x & 7) * 64;
  const int t = threadIdx.x;
#pragma unroll
  for (int i = 0; i < 16; ++i) {
    int e = t + i * 256;
    int kk = e >> 6, aa = e & 63;
    s[aa][kk] = f2bf(pw[(size_t)(k0 + kk) * Aa + a0 + aa]);
  }
  __syncthreads();
#pragma unroll
  for (int i = 0; i < 16; ++i) {
    int e = t + i * 256;
    int aa = e >> 6, kk = e & 63;
    pwT[(size_t)(a0 + aa) * Hh + k0 + kk] = s[aa][kk];
  }
}

// ---------------------------------------------------------------------------
// k0_gemm (m97-style): logits += sum_a tanh((hid@pw)[m][a] + pb[a]) * sw[a]
// 128x128 tile, BK=32, both operands bf16, staged via global_load_lds(16B).
// LDS layout: [row][k] 32 ushort = 64 B rows, unpadded (wave-uniform+lane*16
// constraint). Hot loop per wave: 4 global_load_lds + 8 ds_read_b128 +
// 16 MFMA. Grid (256 m-tiles, 4 n-tiles), 4 waves (2x2).
// ---------------------------------------------------------------------------
__global__ __launch_bounds__(256) void k0_gemm(
    const ushort* __restrict__ hidb, const ushort* __restrict__ pwT,
    const float* __restrict__ pb, const float* __restrict__ sw,
    float* __restrict__ logits) {
  __shared__ ushort At[128 * 32];  // 8 KB
  __shared__ ushort Bt[128 * 32];  // 8 KB
  const int tid = threadIdx.x;
  const int w = tid >> 6, lane = tid & 63;
  const int lc = lane & 15, lq = lane >> 4;
  const int wm = w >> 1, wn = w & 1;
  const int m0 = blockIdx.x * 128, bn = blockIdx.y;

  // staging: wave w owns row-chunks c0=2w, c1=2w+1 (16 rows each);
  // lane -> row = 16c + (lane>>2), k-quarter = (lane&3)*8 ushort.
  const int c0 = w * 2, c1 = w * 2 + 1;
  const int ra = lane >> 2;
  const int kq = (lane & 3) * 8;
  const ushort* Ag0 = hidb + (size_t)(m0 + c0 * 16 + ra) * Hh + kq;
  const ushort* Ag1 = hidb + (size_t)(m0 + c1 * 16 + ra) * Hh + kq;
  const ushort* Bg0 = pwT + (size_t)(bn * 128 + c0 * 16 + ra) * Hh + kq;
  const ushort* Bg1 = pwT + (size_t)(bn * 128 + c1 * 16 + ra) * Hh + kq;
  ushort* Al0 = At + c0 * 512;  // 16 rows * 32 ushort
  ushort* Al1 = At + c1 * 512;
  ushort* Bl0 = Bt + c0 * 512;
  ushort* Bl1 = Bt + c1 * 512;

  f32x4 acc[4][4];
#pragma unroll
  for (int mi = 0; mi < 4; ++mi)
#pragma unroll
    for (int ni = 0; ni < 4; ++ni) acc[mi][ni] = (f32x4){0.f, 0.f, 0.f, 0.f};

  int aoff[4], boff[4];
#pragma unroll
  for (int i = 0; i < 4; ++i) {
    aoff[i] = (wm * 64 + i * 16 + lc) * 32 + lq * 8;
    boff[i] = (wn * 64 + i * 16 + lc) * 32 + lq * 8;
  }

  for (int kb = 0; kb < 16; ++kb) {
    GLOAD_LDS16(Ag0 + kb * 32, Al0);
    GLOAD_LDS16(Ag1 + kb * 32, Al1);
    GLOAD_LDS16(Bg0 + kb * 32, Bl0);
    GLOAD_LDS16(Bg1 + kb * 32, Bl1);
    __syncthreads();  // drains vmcnt: LDS tiles ready
    s16x8 af[4], bf[4];
#pragma unroll
    for (int mi = 0; mi < 4; ++mi) af[mi] = *(const s16x8*)(At + aoff[mi]);
#pragma unroll
    for (int ni = 0; ni < 4; ++ni) bf[ni] = *(const s16x8*)(Bt + boff[ni]);
#pragma unroll
    for (int mi = 0; mi < 4; ++mi)
#pragma unroll
      for (int ni = 0; ni < 4; ++ni)
        acc[mi][ni] = __builtin_amdgcn_mfma_f32_16x16x32_bf16(
            af[mi], bf[ni], acc[mi][ni], 0, 0, 0);
    __syncthreads();  // all waves done reading before next overwrite
  }

  // epilogue: tanh(x + pb[n]) * sw[n], reduce over n, atomicAdd into logits
  float pbv[4], swv[4];
#pragma unroll
  for (int ni = 0; ni < 4; ++ni) {
    int n = bn * 128 + wn * 64 + ni * 16 + lc;
    pbv[ni] = pb[n];
    swv[ni] = sw[n];
  }
#pragma unroll
  for (int mi = 0; mi < 4; ++mi) {
#pragma unroll
    for (int r = 0; r < 4; ++r) {
      float s = 0.f;
#pragma unroll
      for (int ni = 0; ni < 4; ++ni) {
        float x = acc[mi][ni][r] + pbv[ni];
        float e = __expf(2.f * x);
        float th = 1.f - 2.f / (e + 1.f);
        s = fmaf(th, swv[ni], s);
      }
      s += __shfl_xor(s, 1);
      s += __shfl_xor(s, 2);
      s += __shfl_xor(s, 4);
      s += __shfl_xor(s, 8);
      if (lc == 0) {
        int m = m0 + wm * 64 + mi * 16 + lq * 4 + r;
        atomicAdd(&logits[m], s);
      }
    }
  }
}

// ---------------------------------------------------------------------------
// K2: actT[b][c][l] = relu(act[b][l][c]);  dinv[b][l] = 1/max(sum_c relu, 1)
// ---------------------------------------------------------------------------
__global__ void k2_transpose(const float* __restrict__ act,
                             float* __restrict__ actT,
                             float* __restrict__ dinv) {
  __shared__ float t64[64][65];
  const int b = blockIdx.x >> 6;
  const int l0 = (blockIdx.x & 63) * 64;
  const int tid = threadIdx.x;
#pragma unroll
  for (int i = 0; i < 16; ++i) {
    int e = tid + i * 256;
    int l = e >> 6, c = e & 63;
    float v = act[((size_t)(b * Ll + l0 + l)) * Cc + c];
    t64[l][c] = fmaxf(v, 0.f);
  }
  __syncthreads();
  if (tid < 64) {
    float s = 0.f;
#pragma unroll 8
    for (int c = 0; c < 64; ++c) s += t64[tid][c];
    dinv[b * Ll + l0 + tid] = 1.0f / fmaxf(s, 1.0f);
  }
#pragma unroll
  for (int i = 0; i < 16; ++i) {
    int e = tid + i * 256;
    int c = e >> 6, lq = e & 63;
    actT[((size_t)(b * Cc + c)) * Ll + l0 + lq] = t64[lq][c];
  }
}

// ---------------------------------------------------------------------------
// K3: per (b,c) row softmax over L -> weights output (fp32) + bf16 copy.
// ---------------------------------------------------------------------------
__global__ void k3_softmax(const float* __restrict__ actT,
                           const float* __restrict__ logits,
                           float* __restrict__ wout,
                           ushort* __restrict__ wb16,
                           int* __restrict__ hasany) {
  __shared__ float rmax[4], rcnt[4], rsum[4];
  const int bid = blockIdx.x;  // b*64+c
  const int b = bid >> 6;
  const int tid = threadIdx.x;
  const float* arow = actT + (size_t)bid * Ll;

  float xs[16];
  float lmax = NEGV, fcnt = 0.f;
#pragma unroll
  for (int i = 0; i < 16; ++i) {
    int l = tid + i * 256;
    float a = arow[l];
    float x;
    if (a > 0.f) {
      x = logits[b * Ll + l] + log1pf(a);
      fcnt += 1.f;
    } else {
      x = NEGV;
    }
    xs[i] = x;
    lmax = fmaxf(lmax, x);
  }
#pragma unroll
  for (int m = 32; m >= 1; m >>= 1) {
    lmax = fmaxf(lmax, __shfl_xor(lmax, m));
    fcnt += __shfl_xor(fcnt, m);
  }
  if ((tid & 63) == 0) { rmax[tid >> 6] = lmax; rcnt[tid >> 6] = fcnt; }
  __syncthreads();
  float m4 = fmaxf(fmaxf(rmax[0], rmax[1]), fmaxf(rmax[2], rmax[3]));
  float call = rcnt[0] + rcnt[1] + rcnt[2] + rcnt[3];

  float lsum = 0.f;
#pragma unroll
  for (int i = 0; i < 16; ++i) {
    float e = expf(xs[i] - m4);
    xs[i] = e;
    lsum += e;
  }
#pragma unroll
  for (int m = 32; m >= 1; m >>= 1) lsum += __shfl_xor(lsum, m);
  if ((tid & 63) == 0) rsum[tid >> 6] = lsum;
  __syncthreads();
  float s = rsum[0] + rsum[1] + rsum[2] + rsum[3];
  int any = call > 0.5f;
  float inv = any ? 1.0f / s : 0.f;
#pragma unroll
  for (int i = 0; i < 16; ++i) {
    float wv = xs[i] * inv;
    wout[(size_t)bid * Ll + tid + i * 256] = wv;
    wb16[(size_t)bid * Ll + tid + i * 256] = f2bf(wv);
  }
  if (tid == 0) hasany[bid] = any;
}

// ---------------------------------------------------------------------------
// K5: bf16 MFMA partial GEMM: pbuf[kz][b][c][h] = sum_{l in slice} w*hid.
// ---------------------------------------------------------------------------
__global__ __launch_bounds__(256) void k5_mfma(
    const ushort* __restrict__ wb16, const float* __restrict__ hid,
    float* __restrict__ pbuf) {
  const int b = blockIdx.x, nt = blockIdx.y, kz = blockIdx.z;
  const int tid = threadIdx.x;
  const int w = tid >> 6, lane = tid & 63;
  const int lc = lane & 15, lq = lane >> 4;
  const int h0 = nt * 128 + w * 32;

  f32x4 acc[4][2];
#pragma unroll
  for (int mi = 0; mi < 4; ++mi)
#pragma unroll
    for (int ni = 0; ni < 2; ++ni) acc[mi][ni] = (f32x4){0.f, 0.f, 0.f, 0.f};

  const ushort* Abase =
      wb16 + (size_t)b * Cc * Ll + (size_t)lc * Ll + kz * 256 + lq * 8;
  const float* Bbase =
      hid + ((size_t)(b * Ll + kz * 256 + lq * 8)) * Hh + h0 + lc;

  for (int kb = 0; kb < 8; ++kb) {
    s16x8 af[4];
#pragma unroll
    for (int mi = 0; mi < 4; ++mi)
      af[mi] = *(const s16x8*)(Abase + (size_t)mi * 16 * Ll + kb * 32);
    s16x8 bf[2];
#pragma unroll
    for (int ni = 0; ni < 2; ++ni) {
      const float* bp = Bbase + (size_t)kb * 32 * Hh + ni * 16;
      uint u0 = bfpack2(bp[0 * Hh], bp[1 * Hh]);
      uint u1 = bfpack2(bp[2 * Hh], bp[3 * Hh]);
      uint u2 = bfpack2(bp[4 * Hh], bp[5 * Hh]);
      uint u3 = bfpack2(bp[6 * Hh], bp[7 * Hh]);
      union { uint4 u4; s16x8 s; } cv;
      cv.u4 = (uint4){u0, u1, u2, u3};
      bf[ni] = cv.s;
    }
#pragma unroll
    for (int mi = 0; mi < 4; ++mi)
#pragma unroll
      for (int ni = 0; ni < 2; ++ni)
        acc[mi][ni] = __builtin_amdgcn_mfma_f32_16x16x32_bf16(
            af[mi], bf[ni], acc[mi][ni], 0, 0, 0);
  }

  const size_t obase = ((size_t)(kz * Bb + b)) * Cc * Hh;
#pragma unroll
  for (int mi = 0; mi < 4; ++mi)
#pragma unroll
    for (int ni = 0; ni < 2; ++ni)
#pragma unroll
      for (int r = 0; r < 4; ++r)
        pbuf[obase + (size_t)(mi * 16 + lq * 4 + r) * Hh + h0 + ni * 16 + lc] =
            acc[mi][ni][r];
}

// ---------------------------------------------------------------------------
// K6: reduce 16 partials + fallback substitution.
// ---------------------------------------------------------------------------
__global__ void k6_reduce(const float* __restrict__ pbuf,
                          const int* __restrict__ hasany,
                          const float* __restrict__ hid,
                          float* __restrict__ cctx) {
  int idx = blockIdx.x * 256 + threadIdx.x;  // 0..262143
  float s = 0.f;
#pragma unroll
  for (int z = 0; z < 16; ++z) s += pbuf[(size_t)z * 262144 + idx];
  int bc = idx >> 9, b = idx >> 15, h = idx & 511;
  cctx[idx] = hasany[bc] ? s : hid[((size_t)(b * Ll + Ll - 1)) * Hh + h];
}

// ---------------------------------------------------------------------------
// K7: attended = mask ? (mix @ cctx) * gate : hidden
// ---------------------------------------------------------------------------
__global__ __launch_bounds__(256, 2) void k7_out(
    const float* __restrict__ hid, const float* __restrict__ act,
    const float* __restrict__ dinv, const float* __restrict__ cctx,
    const int* __restrict__ mask, const int* __restrict__ cnt,
    const int* __restrict__ cmax, float* __restrict__ out) {
  __shared__ float mix[32 * 68];
  __shared__ float gateb[32];
  __shared__ int maskb[32];
  const int b = blockIdx.x;
  const int l0 = blockIdx.y * 32;
  const int tid = threadIdx.x;
  const float maxcf = fmaxf((float)cmax[b], 1.0f);

#pragma unroll
  for (int i = 0; i < 2; ++i) {
    int q = tid + i * 256;
    int t = q >> 4, cq = q & 15;
    float4 a4 = *(const float4*)(act + ((size_t)(b * Ll + l0 + t)) * Cc + cq * 4);
    float dv = dinv[b * Ll + l0 + t];
    a4.x = fmaxf(a4.x, 0.f) * dv;
    a4.y = fmaxf(a4.y, 0.f) * dv;
    a4.z = fmaxf(a4.z, 0.f) * dv;
    a4.w = fmaxf(a4.w, 0.f) * dv;
    *(float4*)(mix + t * 68 + cq * 4) = a4;
  }
  if (tid < 32) {
    int l = l0 + tid;
    maskb[tid] = mask[b * Ll + l];
    gateb[tid] = 1.0f + (float)cnt[b * Ll + l] / maxcf;
  }
  __syncthreads();

  const int tt = tid >> 6;
  const int h = (tid & 63) * 8;
  float acc[8][8];
#pragma unroll
  for (int t = 0; t < 8; ++t)
#pragma unroll
    for (int u = 0; u < 8; ++u) acc[t][u] = 0.f;

#pragma unroll 4
  for (int c = 0; c < 64; ++c) {
    float4 cA = *(const float4*)(cctx + ((size_t)(b * Cc + c)) * Hh + h);
    float4 cB = *(const float4*)(cctx + ((size_t)(b * Cc + c)) * Hh + h + 4);
    float cv[8] = {cA.x, cA.y, cA.z, cA.w, cB.x, cB.y, cB.z, cB.w};
#pragma unroll
    for (int t = 0; t < 8; ++t) {
      float mv = mix[(tt * 8 + t) * 68 + c];
#pragma unroll
      for (int u = 0; u < 8; ++u) acc[t][u] = fmaf(mv, cv[u], acc[t][u]);
    }
  }
#pragma unroll
  for (int t = 0; t < 8; ++t) {
    int tok = tt * 8 + t;
    size_t off = ((size_t)(b * Ll + l0 + tok)) * Hh + h;
    float4 o1, o2;
    if (maskb[tok]) {
      float g = gateb[tok];
      o1 = make_float4(acc[t][0] * g, acc[t][1] * g, acc[t][2] * g, acc[t][3] * g);
      o2 = make_float4(acc[t][4] * g, acc[t][5] * g, acc[t][6] * g, acc[t][7] * g);
    } else {
      o1 = *(const float4*)(hid + off);
      o2 = *(const float4*)(hid + off + 4);
    }
    *(float4*)(out + off) = o1;
    *(float4*)(out + off + 4) = o2;
  }
}

// ---------------------------------------------------------------------------
extern "C" void kernel_launch(void* const* d_in, const int* in_sizes, int n_in,
                              void* d_out, int out_size, void* d_ws,
                              size_t ws_size, hipStream_t stream) {
  const float* hid = (const float*)d_in[0];
  const int* mask = (const int*)d_in[1];
  const int* cnt = (const int*)d_in[2];
  const float* act = (const float*)d_in[3];
  const float* pw = (const float*)d_in[4];
  const float* pb = (const float*)d_in[5];
  const float* sw = (const float*)d_in[6];
  const float* sb = (const float*)d_in[7];

  float* out_att = (float*)d_out;                 // (B,L,H)
  float* out_w = out_att + (size_t)Bb * Ll * Hh;  // (B,C,L)

  float* ws = (float*)d_ws;
  float* cctx = ws;                               // 262144 f
  int* cmaxi = (int*)(ws + 262144);               // 8 i
  float* logits = ws + 262152;                    // 32768 f
  float* actT = ws + 294920;                      // 2097152 f
  float* dinv = ws + 2392072;                     // 32768 f
  int* hasany = (int*)(ws + 2424840);             // 512 i
  ushort* pwT = (ushort*)(ws + 2425352);          // 262144 bf16
  ushort* wb16 = (ushort*)(ws + 2556424);         // 2097152 bf16
  ushort* hidb = (ushort*)(ws + 3605000);         // 16777216 bf16 (32 MB)
  // pbuf aliases hidb: hidb is dead after k0_gemm; k5 writes pbuf later.
  float* pbuf = ws + 3605000;                     // 4194304 f (16 MB)

  hipMemsetAsync(cmaxi, 0, 8 * sizeof(int), stream);

  k_conv<<<8192, 256, 0, stream>>>(hid, hidb);
  k_init<<<128, 256, 0, stream>>>(cnt, sb, logits, cmaxi);
  kT_pw<<<64, 256, 0, stream>>>(pw, pwT);
  k0_gemm<<<dim3(256, 4), 256, 0, stream>>>(hidb, pwT, pb, sw, logits);
  k2_transpose<<<512, 256, 0, stream>>>(act, actT, dinv);
  k3_softmax<<<512, 256, 0, stream>>>(actT, logits, out_w, wb16, hasany);
  k5_mfma<<<dim3(8, 4, 16), 256, 0, stream>>>(wb16, hid, pbuf);
  k6_reduce<<<1024, 256, 0, stream>>>(pbuf, hasany, hid, cctx);
  k7_out<<<dim3(8, 128), 256, 0, stream>>>(hid, act, dinv, cctx, mask, cnt,
                                           cmaxi, out_att);
}